// Round 1
// baseline (2817.136 us; speedup 1.0000x reference)
//
#include <hip/hip_runtime.h>

// ---------------------------------------------------------------------------
// DualRealConvTasNet fp32 baseline.
// Both branches (real/imag) batched together: encoder/TCN batch P=8, decoder 16.
// All activation tensors: [batch][chan][row of ST floats], data at [HALO + t],
// halo/pad zeroed so k=3 convs (and transposed convs as pad=2 convs) need no
// boundary logic inside the GEMM tiles.
// ---------------------------------------------------------------------------

#define ST   2064   // row stride in floats (>= 8 + 1999 + conv read overhang)
#define HALO 8

// workspace layout (float offsets)
#define OFF_R1    0ULL          // f0 | f1  (later y, later d2)  : 16,908,288
#define OFF_F1    8454144ULL
#define OFF_D1    16908288ULL   // d1                            : 16,908,288
#define OFF_F2    33816576ULL   // f2 (encoder output)           :  8,454,144
#define OFF_O     42270720ULL   // o  [8][128][ST]               :  2,113,536
#define OFF_GA    44384256ULL   // g ping                        :    528,384
#define OFF_GB    44912640ULL   // g pong                        :    528,384
#define OFF_W     45441024ULL   // transposed weights
#define OFF_WENC1 (OFF_W + 0ULL)
#define OFF_WENC2 (OFF_W + 786432ULL)
#define OFF_WDEC1 (OFF_W + 1572864ULL)
#define OFF_WDEC2 (OFF_W + 2359296ULL)
#define OFF_MGIN  (OFF_W + 3145728ULL)   // [512][128]
#define OFF_MGOUT (OFF_W + 3211264ULL)   // [128][1024]
#define OFF_W1T   (OFF_W + 3342336ULL)   // [24][128][32]
#define OFF_WSUMT (OFF_W + 3440640ULL)   // [24][32][128]
#define OFF_BSUM  (OFF_W + 3538944ULL)   // [24][128]
// total floats: 48,983,040  (~196 MB)

__device__ __forceinline__ float prelu_f(float x, float a) { return x >= 0.f ? x : a * x; }

// ---------------------------------------------------------------------------
// Weight prep: transposes into GEMM-friendly layouts. task = blockIdx.y.
// ---------------------------------------------------------------------------
__global__ __launch_bounds__(256) void prep_weights(
    const float* __restrict__ ew1, const float* __restrict__ ew2,
    const float* __restrict__ dw1, const float* __restrict__ dw2,
    const float* __restrict__ mgin_w, const float* __restrict__ mgout_w,
    const float* __restrict__ bw1, const float* __restrict__ brw,
    const float* __restrict__ brb, const float* __restrict__ bsw,
    const float* __restrict__ bsb, float* __restrict__ ws)
{
    const int task = blockIdx.y;
    const int idx  = blockIdx.x * 256 + threadIdx.x;
    const int stride = gridDim.x * 256;
    if (task < 4) {
        // conv3 weights -> wT[c][j][o]; decoder: flip k + swap in/out
        const float* src = (task == 0) ? ew1 : (task == 1) ? ew2 : (task == 2) ? dw1 : dw2;
        float* dst = ws + OFF_WENC1 + (size_t)task * 786432ULL;
        const bool dec = (task >= 2);
        for (int n = idx; n < 512 * 3 * 512; n += stride) {
            int o = n & 511, j = (n >> 9) % 3, c = n / 1536;
            dst[n] = dec ? src[(size_t)c * 1536 + o * 3 + (2 - j)]
                         : src[(size_t)o * 1536 + c * 3 + j];
        }
    } else if (task == 4) {          // mg_in_w [128][512] -> [512][128]
        float* dst = ws + OFF_MGIN;
        for (int n = idx; n < 65536; n += stride) {
            int o = n & 127, c = n >> 7;
            dst[n] = mgin_w[(size_t)o * 512 + c];
        }
    } else if (task == 5) {          // mg_out_w [1024][128] -> [128][1024]
        float* dst = ws + OFF_MGOUT;
        for (int n = idx; n < 131072; n += stride) {
            int m = n & 1023, c = n >> 10;
            dst[n] = mgout_w[(size_t)m * 128 + c];
        }
    } else if (task == 6) {          // blk_w1 [24][32][128] -> [24][128][32]
        float* dst = ws + OFF_W1T;
        for (int n = idx; n < 98304; n += stride) {
            int cc = n & 31, C = (n >> 5) & 127, i = n >> 12;
            dst[n] = bw1[(size_t)i * 4096 + cc * 128 + C];
        }
    } else if (task == 7) {          // wsumT[i][cc][C] = sw (+ rw if i<23)
        float* dst = ws + OFF_WSUMT;
        for (int n = idx; n < 98304; n += stride) {
            int C = n & 127, cc = (n >> 7) & 31, i = n >> 12;
            float v = bsw[(size_t)i * 4096 + C * 32 + cc];
            if (i < 23) v += brw[(size_t)i * 4096 + C * 32 + cc];
            dst[n] = v;
        }
    } else {                         // bsum[i][C]
        float* dst = ws + OFF_BSUM;
        for (int n = idx; n < 3072; n += stride) {
            int i = n >> 7;
            float v = bsb[n];
            if (i < 23) v += brb[n];
            dst[n] = v;
        }
    }
}

// ---------------------------------------------------------------------------
// Encoder conv0: 1->512, k=16, stride 8.  grid (8, 64, 8 batch)
// ---------------------------------------------------------------------------
__global__ __launch_bounds__(256) void enc0_kernel(
    const float* __restrict__ xr, const float* __restrict__ xi,
    const float* __restrict__ w0, float* __restrict__ f0)
{
    const int t  = blockIdx.x * 256 + threadIdx.x;
    const int c0 = blockIdx.y * 8;
    const int b  = blockIdx.z;
    if (t >= 1999) return;
    const float* x = (b < 4) ? (xr + (size_t)b * 16000) : (xi + (size_t)(b - 4) * 16000);
    float xv[16];
    const int base = t * 8;
#pragma unroll
    for (int k = 0; k < 16; k++) xv[k] = x[base + k];
#pragma unroll
    for (int cq = 0; cq < 8; cq++) {
        const float* w = w0 + (size_t)(c0 + cq) * 16;
        float acc = 0.f;
#pragma unroll
        for (int k = 0; k < 16; k++) acc = fmaf(xv[k], w[k], acc);
        f0[(size_t)(b * 512 + c0 + cq) * ST + HALO + t] = acc;
    }
}

// ---------------------------------------------------------------------------
// Generic 512->512 k=3 conv (+PReLU).  PAD=0: valid conv; PAD=2: tconv form.
// Tile: 64 oc x 128 t, BK=16.  grid (tTiles=16, 8, B)
// ---------------------------------------------------------------------------
template <int PAD>
__global__ __launch_bounds__(256) void conv3_kernel(
    const float* __restrict__ in, float* __restrict__ out,
    const float* __restrict__ wT, const float* __restrict__ alpha_p, int Tout)
{
    __shared__ float As[3072];       // [c16][j3][o64]
    __shared__ float Bs[16][136];    // in window [t0-4, t0+132)
    const int tid = threadIdx.x;
    const int t0  = blockIdx.x * 128;
    const int ob  = blockIdx.y * 64;
    const int b   = blockIdx.z;
    const float* inb = in + (size_t)b * 512 * ST;

    float acc[8][4];
#pragma unroll
    for (int i = 0; i < 8; i++)
#pragma unroll
        for (int k = 0; k < 4; k++) acc[i][k] = 0.f;

    const int tx = tid & 31;   // 32 t-groups of 4
    const int ty = tid >> 5;   // 8 o-groups of 8

    for (int c0 = 0; c0 < 512; c0 += 16) {
#pragma unroll
        for (int r = 0; r < 3; r++) {                 // stage A (768 float4)
            int n4 = tid + r * 256;
            int o4 = n4 & 15, j = (n4 >> 4) % 3, c = n4 / 48;
            float4 v = *(const float4*)(wT + (size_t)(c0 + c) * 1536 + j * 512 + ob + o4 * 4);
            *(float4*)(&As[(c * 3 + j) * 64 + o4 * 4]) = v;
        }
        {                                             // stage B (544 float4)
            const float* src = inb + HALO + t0 - 4;
            for (int v4 = tid; v4 < 544; v4 += 256) {
                int c = v4 / 34, p = v4 % 34;
                *(float4*)(&Bs[c][p * 4]) = *(const float4*)(src + (size_t)(c0 + c) * ST + p * 4);
            }
        }
        __syncthreads();
#pragma unroll 2
        for (int c = 0; c < 16; c++) {
            float bwin[8];
            {
                float4 b0 = *(const float4*)(&Bs[c][tx * 4 + (PAD == 0 ? 4 : 0)]);
                float4 b1 = *(const float4*)(&Bs[c][tx * 4 + (PAD == 0 ? 4 : 0) + 4]);
                bwin[0] = b0.x; bwin[1] = b0.y; bwin[2] = b0.z; bwin[3] = b0.w;
                bwin[4] = b1.x; bwin[5] = b1.y; bwin[6] = b1.z; bwin[7] = b1.w;
            }
#pragma unroll
            for (int j = 0; j < 3; j++) {
                float a[8];
                *(float4*)(&a[0]) = *(const float4*)(&As[(c * 3 + j) * 64 + ty * 8]);
                *(float4*)(&a[4]) = *(const float4*)(&As[(c * 3 + j) * 64 + ty * 8 + 4]);
                const int qo = (PAD == 0) ? j : (j + 2);
#pragma unroll
                for (int kk = 0; kk < 4; kk++) {
                    const float bv = bwin[kk + qo];
#pragma unroll
                    for (int oi = 0; oi < 8; oi++) acc[oi][kk] = fmaf(a[oi], bv, acc[oi][kk]);
                }
            }
        }
        __syncthreads();
    }

    const float alpha = *alpha_p;
    const int tbase = t0 + tx * 4;
#pragma unroll
    for (int oi = 0; oi < 8; oi++) {
        float* orow = out + (size_t)(b * 512 + ob + ty * 8 + oi) * ST + HALO + tbase;
        if (tbase + 3 < Tout) {
            float4 v = make_float4(prelu_f(acc[oi][0], alpha), prelu_f(acc[oi][1], alpha),
                                   prelu_f(acc[oi][2], alpha), prelu_f(acc[oi][3], alpha));
            *(float4*)orow = v;
        } else {
#pragma unroll
            for (int kk = 0; kk < 4; kk++)
                if (tbase + kk < Tout) orow[kk] = prelu_f(acc[oi][kk], alpha);
        }
    }
}

// ---------------------------------------------------------------------------
// mg_in: o = mg_in_w @ f2 + b  (512->128), fused g0 = prelu(pw1_0(o)).
// grid (32 t-tiles of 64, 8 batch)
// ---------------------------------------------------------------------------
__global__ __launch_bounds__(256) void mgin_kernel(
    const float* __restrict__ f2, float* __restrict__ o_buf, float* __restrict__ g_out,
    const float* __restrict__ wT, const float* __restrict__ bias,
    const float* __restrict__ w1T0, const float* __restrict__ b1_0,
    const float* __restrict__ a1_0)
{
    __shared__ float Bs[16][64];
    __shared__ float As[16][128];
    __shared__ float o_lds[128][64];
    const int tid = threadIdx.x;
    const int t0  = blockIdx.x * 64;
    const int b   = blockIdx.y;
    const float* f2b = f2 + (size_t)b * 512 * ST + HALO + t0;

    float acc[8][4];
#pragma unroll
    for (int i = 0; i < 8; i++)
#pragma unroll
        for (int k = 0; k < 4; k++) acc[i][k] = 0.f;
    const int tx = tid & 15, ty = tid >> 4;

    for (int c0 = 0; c0 < 512; c0 += 16) {
        {
            int c = tid >> 4, p = tid & 15;
            *(float4*)(&Bs[c][p * 4]) = *(const float4*)(f2b + (size_t)(c0 + c) * ST + p * 4);
        }
#pragma unroll
        for (int r = 0; r < 2; r++) {
            int n4 = tid + r * 256;
            int c = n4 >> 5, m4 = n4 & 31;
            *(float4*)(&As[c][m4 * 4]) = *(const float4*)(wT + (size_t)(c0 + c) * 128 + m4 * 4);
        }
        __syncthreads();
#pragma unroll 2
        for (int c = 0; c < 16; c++) {
            float4 bv = *(const float4*)(&Bs[c][tx * 4]);
            float a[8];
            *(float4*)(&a[0]) = *(const float4*)(&As[c][ty * 8]);
            *(float4*)(&a[4]) = *(const float4*)(&As[c][ty * 8 + 4]);
#pragma unroll
            for (int oi = 0; oi < 8; oi++) {
                acc[oi][0] = fmaf(a[oi], bv.x, acc[oi][0]);
                acc[oi][1] = fmaf(a[oi], bv.y, acc[oi][1]);
                acc[oi][2] = fmaf(a[oi], bv.z, acc[oi][2]);
                acc[oi][3] = fmaf(a[oi], bv.w, acc[oi][3]);
            }
        }
        __syncthreads();
    }

    const int tb = t0 + tx * 4;
#pragma unroll
    for (int oi = 0; oi < 8; oi++) {
        const int o = ty * 8 + oi;
        const float bo = bias[o];
        float vv[4];
#pragma unroll
        for (int kk = 0; kk < 4; kk++) vv[kk] = acc[oi][kk] + bo;
        *(float4*)(&o_lds[o][tx * 4]) = make_float4(vv[0], vv[1], vv[2], vv[3]);
        float* orow = o_buf + (size_t)(b * 128 + o) * ST + HALO + tb;
        if (tb + 3 < 1995) {
            *(float4*)orow = make_float4(vv[0], vv[1], vv[2], vv[3]);
        } else {
#pragma unroll
            for (int kk = 0; kk < 4; kk++)
                if (tb + kk < 1995) orow[kk] = vv[kk];
        }
    }
    __syncthreads();

    // g0 = prelu(w1_0 @ o + b1_0)
    const int t = tid & 63, cg = tid >> 6;
    const float a1 = *a1_0;
    float acc2[8];
#pragma unroll
    for (int q = 0; q < 8; q++) acc2[q] = b1_0[cg * 8 + q];
    for (int C = 0; C < 128; C++) {
        const float ov = o_lds[C][t];
        const float4* wr = (const float4*)(w1T0 + (size_t)C * 32 + cg * 8);
        float4 w0 = wr[0], w1 = wr[1];
        acc2[0] = fmaf(w0.x, ov, acc2[0]); acc2[1] = fmaf(w0.y, ov, acc2[1]);
        acc2[2] = fmaf(w0.z, ov, acc2[2]); acc2[3] = fmaf(w0.w, ov, acc2[3]);
        acc2[4] = fmaf(w1.x, ov, acc2[4]); acc2[5] = fmaf(w1.y, ov, acc2[5]);
        acc2[6] = fmaf(w1.z, ov, acc2[6]); acc2[7] = fmaf(w1.w, ov, acc2[7]);
    }
    const int tt = t0 + t;
    if (tt < 1995) {
#pragma unroll
        for (int q = 0; q < 8; q++)
            g_out[(size_t)(b * 32 + cg * 8 + q) * ST + HALO + tt] = prelu_f(acc2[q], a1);
    }
}

// ---------------------------------------------------------------------------
// One TCN block: h = prelu(dwconv_d(g_in)); o += wsum@h + bsum;
//                g_out = prelu(w1_next @ o + b1_next)   (if has_next)
// grid (32 t-tiles of 64, 8 batch)
// ---------------------------------------------------------------------------
__global__ __launch_bounds__(256) void tcn_kernel(
    const float* __restrict__ g_in, float* __restrict__ g_out, float* __restrict__ o_buf,
    const float* __restrict__ dw, const float* __restrict__ db, const float* __restrict__ a2p,
    const float* __restrict__ wsumT, const float* __restrict__ bsum,
    const float* __restrict__ w1T, const float* __restrict__ b1,
    const float* __restrict__ a1p, int dil, int has_next)
{
    __shared__ float h_lds[32][64];
    __shared__ float o_lds[128][64];
    __shared__ float wsum_lds[4096];
    __shared__ float w1_lds[4096];
    const int tid = threadIdx.x;
    const int t0  = blockIdx.x * 64;
    const int b   = blockIdx.y;

    for (int i = tid; i < 4096; i += 256) wsum_lds[i] = wsumT[i];
    if (has_next)
        for (int i = tid; i < 4096; i += 256) w1_lds[i] = w1T[i];

    const int t = tid & 63, grp = tid >> 6;
    const int tt = t0 + t;

    // step 1: depthwise conv + prelu -> h
    {
        const float a2 = *a2p;
#pragma unroll
        for (int q = 0; q < 8; q++) {
            const int cc = grp * 8 + q;
            const float* grow = g_in + (size_t)(b * 32 + cc) * ST + HALO;
            const float w0 = dw[cc * 3 + 0], w1v = dw[cc * 3 + 1], w2 = dw[cc * 3 + 2];
            float s = db[cc] + w1v * grow[tt];
            const int tm = tt - dil;
            if (tm >= 0) s = fmaf(w0, grow[tm], s);
            const int tp = tt + dil;
            if (tp < 1995) s = fmaf(w2, grow[tp], s);
            h_lds[cc][t] = prelu_f(s, a2);
        }
    }
    __syncthreads();

    // step 2: o += wsum @ h + bsum
    {
        float hv[32];
#pragma unroll
        for (int cc = 0; cc < 32; cc++) hv[cc] = h_lds[cc][t];
        float s[32];
        const float* orow = o_buf + (size_t)(b * 128 + grp * 32) * ST + HALO + tt;
#pragma unroll
        for (int q = 0; q < 32; q++) s[q] = bsum[grp * 32 + q] + orow[(size_t)q * ST];
        for (int cc = 0; cc < 32; cc++) {
            const float h = hv[cc];
            const float4* wrow = (const float4*)&wsum_lds[cc * 128 + grp * 32];
#pragma unroll
            for (int q4 = 0; q4 < 8; q4++) {
                float4 w = wrow[q4];
                s[q4 * 4 + 0] = fmaf(w.x, h, s[q4 * 4 + 0]);
                s[q4 * 4 + 1] = fmaf(w.y, h, s[q4 * 4 + 1]);
                s[q4 * 4 + 2] = fmaf(w.z, h, s[q4 * 4 + 2]);
                s[q4 * 4 + 3] = fmaf(w.w, h, s[q4 * 4 + 3]);
            }
        }
#pragma unroll
        for (int q = 0; q < 32; q++) {
            const int C = grp * 32 + q;
            o_lds[C][t] = s[q];
            if (tt < 1995) o_buf[(size_t)(b * 128 + C) * ST + HALO + tt] = s[q];
        }
    }
    if (!has_next) return;
    __syncthreads();

    // step 3: g_next = prelu(w1_next @ o + b1_next)
    {
        const int ccb = grp * 8;
        const float a1 = *a1p;
        float acc2[8];
#pragma unroll
        for (int q = 0; q < 8; q++) acc2[q] = b1[ccb + q];
        for (int C = 0; C < 128; C++) {
            const float ov = o_lds[C][t];
            const float4* wr = (const float4*)&w1_lds[C * 32 + ccb];
            float4 w0 = wr[0], w1v = wr[1];
            acc2[0] = fmaf(w0.x, ov, acc2[0]);  acc2[1] = fmaf(w0.y, ov, acc2[1]);
            acc2[2] = fmaf(w0.z, ov, acc2[2]);  acc2[3] = fmaf(w0.w, ov, acc2[3]);
            acc2[4] = fmaf(w1v.x, ov, acc2[4]); acc2[5] = fmaf(w1v.y, ov, acc2[5]);
            acc2[6] = fmaf(w1v.z, ov, acc2[6]); acc2[7] = fmaf(w1v.w, ov, acc2[7]);
        }
        if (tt < 1995) {
#pragma unroll
            for (int q = 0; q < 8; q++)
                g_out[(size_t)(b * 32 + ccb + q) * ST + HALO + tt] = prelu_f(acc2[q], a1);
        }
    }
}

// ---------------------------------------------------------------------------
// mask + multiply: m = sigmoid(mg_out_w @ prelu(o) + b); y = m * f2
// grid (32 t-tiles of 64, 4 m-tiles of 256, 8 batch)
// ---------------------------------------------------------------------------
__global__ __launch_bounds__(256) void mask_kernel(
    const float* __restrict__ o_buf, const float* __restrict__ f2, float* __restrict__ y,
    const float* __restrict__ wT, const float* __restrict__ mb,
    const float* __restrict__ a_out_p)
{
    __shared__ float o_lds[128][64];
    __shared__ float w_lds[32][256];
    const int tid = threadIdx.x;
    const int t0  = blockIdx.x * 64;
    const int m0  = blockIdx.y * 256;
    const int b   = blockIdx.z;
    const float ao = *a_out_p;

#pragma unroll
    for (int r = 0; r < 8; r++) {       // stage prelu(o)
        int n4 = tid + r * 256;
        int C = n4 >> 4, p = n4 & 15;
        float4 v = *(const float4*)(o_buf + (size_t)(b * 128 + C) * ST + HALO + t0 + p * 4);
        v.x = prelu_f(v.x, ao); v.y = prelu_f(v.y, ao);
        v.z = prelu_f(v.z, ao); v.w = prelu_f(v.w, ao);
        *(float4*)(&o_lds[C][p * 4]) = v;
    }

    float acc[16][4];
#pragma unroll
    for (int i = 0; i < 16; i++)
#pragma unroll
        for (int k = 0; k < 4; k++) acc[i][k] = 0.f;
    const int tx = tid & 15, my = tid >> 4;

    for (int C0 = 0; C0 < 128; C0 += 32) {
#pragma unroll
        for (int r = 0; r < 8; r++) {
            int n4 = tid + r * 256;
            int c = n4 >> 6, m4 = n4 & 63;
            *(float4*)(&w_lds[c][m4 * 4]) =
                *(const float4*)(wT + (size_t)(C0 + c) * 1024 + m0 + m4 * 4);
        }
        __syncthreads();
#pragma unroll 2
        for (int c = 0; c < 32; c++) {
            float4 bv = *(const float4*)(&o_lds[C0 + c][tx * 4]);
            float a[16];
            *(float4*)(&a[0])  = *(const float4*)(&w_lds[c][my * 16 + 0]);
            *(float4*)(&a[4])  = *(const float4*)(&w_lds[c][my * 16 + 4]);
            *(float4*)(&a[8])  = *(const float4*)(&w_lds[c][my * 16 + 8]);
            *(float4*)(&a[12]) = *(const float4*)(&w_lds[c][my * 16 + 12]);
#pragma unroll
            for (int mm = 0; mm < 16; mm++) {
                acc[mm][0] = fmaf(a[mm], bv.x, acc[mm][0]);
                acc[mm][1] = fmaf(a[mm], bv.y, acc[mm][1]);
                acc[mm][2] = fmaf(a[mm], bv.z, acc[mm][2]);
                acc[mm][3] = fmaf(a[mm], bv.w, acc[mm][3]);
            }
        }
        __syncthreads();
    }

    const int tb = t0 + tx * 4;
#pragma unroll
    for (int mm = 0; mm < 16; mm++) {
        const int mi = m0 + my * 16 + mm;
        const float bb = mb[mi];
        const int F = mi & 511, sidx = mi >> 9;
        const float* f2row = f2 + (size_t)(b * 512 + F) * ST + HALO + tb;
        float* yrow = y + (size_t)((b * 2 + sidx) * 512 + F) * ST + HALO + tb;
#pragma unroll
        for (int kk = 0; kk < 4; kk++) {
            if (tb + kk < 1995) {
                const float mval = 1.f / (1.f + __expf(-(acc[mm][kk] + bb)));
                yrow[kk] = mval * f2row[kk];
            }
        }
    }
}

// ---------------------------------------------------------------------------
// Decoder tconv3: 512->1, k=16, stride 8.  Exactly 2 taps per output sample.
// grid (63 tau-tiles of 256, 16 batch)
// ---------------------------------------------------------------------------
__global__ __launch_bounds__(256) void dec3_kernel(
    const float* __restrict__ d2, const float* __restrict__ w3, float* __restrict__ out)
{
    __shared__ float tile[512][34];
    const int tid = threadIdx.x;
    const int bb  = blockIdx.y;
    const int tau0 = blockIdx.x * 256;
    const int tbase = (tau0 >> 3) - 1;
    const float* src = d2 + (size_t)bb * 512 * ST + HALO + tbase;
    for (int n = tid; n < 512 * 34; n += 256) {
        int o = n / 34, i = n % 34;
        tile[o][i] = src[(size_t)o * ST + i];
    }
    __syncthreads();

    const int tau = tau0 + tid;
    if (tau >= 16000) return;
    const int k1 = tau & 7;
    const int t1l = (tid >> 3) + 1;
    float acc = 0.f;
#pragma unroll 8
    for (int o = 0; o < 512; o++) {
        acc = fmaf(tile[o][t1l],     w3[o * 16 + k1],     acc);
        acc = fmaf(tile[o][t1l - 1], w3[o * 16 + 8 + k1], acc);
    }
    const int p = bb >> 1, s = bb & 1;
    const int ri = p >> 2, bq = p & 3;
    out[(size_t)((ri * 4 + bq) * 2 + s) * 16000 + tau] = acc;
}

// ---------------------------------------------------------------------------
extern "C" void kernel_launch(void* const* d_in, const int* in_sizes, int n_in,
                              void* d_out, int out_size, void* d_ws, size_t ws_size,
                              hipStream_t stream)
{
    (void)in_sizes; (void)n_in; (void)out_size; (void)ws_size;
    float* ws = (float*)d_ws;
    const float* x_real   = (const float*)d_in[0];
    const float* x_imag   = (const float*)d_in[1];
    const float* enc_w0   = (const float*)d_in[2];
    const float* enc_w1   = (const float*)d_in[3];
    const float* enc_w2   = (const float*)d_in[4];
    const float* enc_a    = (const float*)d_in[5];
    const float* mg_in_w  = (const float*)d_in[6];
    const float* mg_in_b  = (const float*)d_in[7];
    const float* blk_w1   = (const float*)d_in[8];
    const float* blk_b1   = (const float*)d_in[9];
    const float* blk_a1   = (const float*)d_in[10];
    const float* blk_dw   = (const float*)d_in[11];
    const float* blk_db   = (const float*)d_in[12];
    const float* blk_a2   = (const float*)d_in[13];
    const float* blk_rw   = (const float*)d_in[14];
    const float* blk_rb   = (const float*)d_in[15];
    const float* blk_sw   = (const float*)d_in[16];
    const float* blk_sb   = (const float*)d_in[17];
    const float* mg_out_a = (const float*)d_in[18];
    const float* mg_out_w = (const float*)d_in[19];
    const float* mg_out_b = (const float*)d_in[20];
    const float* dec_w1   = (const float*)d_in[21];
    const float* dec_w2   = (const float*)d_in[22];
    const float* dec_a    = (const float*)d_in[23];
    const float* dec_w3   = (const float*)d_in[24];
    float* out = (float*)d_out;

    float* f0   = ws + OFF_R1;
    float* f1   = ws + OFF_F1;
    float* f2   = ws + OFF_F2;
    float* obuf = ws + OFF_O;
    float* gA   = ws + OFF_GA;
    float* gB   = ws + OFF_GB;
    float* ybuf = ws + OFF_R1;   // reuses f0|f1
    float* d1   = ws + OFF_D1;
    float* d2   = ws + OFF_R1;   // reuses y after dec1

    const dim3 blk(256);

    // zero R1+D1 (f0/f1/d1 halos & pads must be 0 for the k=3 conv windows)
    hipMemsetAsync(ws, 0, (size_t)2 * 16908288ULL * 4, stream);

    prep_weights<<<dim3(64, 9), blk, 0, stream>>>(enc_w1, enc_w2, dec_w1, dec_w2,
        mg_in_w, mg_out_w, blk_w1, blk_rw, blk_rb, blk_sw, blk_sb, ws);

    enc0_kernel<<<dim3(8, 64, 8), blk, 0, stream>>>(x_real, x_imag, enc_w0, f0);
    conv3_kernel<0><<<dim3(16, 8, 8), blk, 0, stream>>>(f0, f1, ws + OFF_WENC1, enc_a + 0, 1997);
    conv3_kernel<0><<<dim3(16, 8, 8), blk, 0, stream>>>(f1, f2, ws + OFF_WENC2, enc_a + 1, 1995);

    mgin_kernel<<<dim3(32, 8), blk, 0, stream>>>(f2, obuf, gA, ws + OFF_MGIN, mg_in_b,
        ws + OFF_W1T, blk_b1, blk_a1);

    for (int i = 0; i < 24; i++) {
        const int dil = 1 << (i & 7);
        const int has_next = (i < 23) ? 1 : 0;
        const float* gi = (i & 1) ? gB : gA;
        float* go       = (i & 1) ? gA : gB;
        tcn_kernel<<<dim3(32, 8), blk, 0, stream>>>(gi, go, obuf,
            blk_dw + i * 96, blk_db + i * 32, blk_a2 + i,
            ws + OFF_WSUMT + (size_t)i * 4096, ws + OFF_BSUM + (size_t)i * 128,
            ws + OFF_W1T + (size_t)(has_next ? (i + 1) : 0) * 4096,
            blk_b1 + (has_next ? (i + 1) : 0) * 32,
            blk_a1 + (has_next ? (i + 1) : 0),
            dil, has_next);
    }

    // re-zero R1 before y is written over stale f0/f1 data (pads must be 0)
    hipMemsetAsync(ws, 0, (size_t)16908288ULL * 4, stream);

    mask_kernel<<<dim3(32, 4, 8), blk, 0, stream>>>(obuf, f2, ybuf,
        ws + OFF_MGOUT, mg_out_b, mg_out_a);

    conv3_kernel<2><<<dim3(16, 8, 16), blk, 0, stream>>>(ybuf, d1, ws + OFF_WDEC1, dec_a + 0, 1997);
    conv3_kernel<2><<<dim3(16, 8, 16), blk, 0, stream>>>(d1, d2, ws + OFF_WDEC2, dec_a + 1, 1999);

    dec3_kernel<<<dim3(63, 16), blk, 0, stream>>>(d2, dec_w3, out);
}

// Round 3
// 1214.367 us; speedup vs baseline: 2.3198x; 2.3198x over previous
//
#include <hip/hip_runtime.h>

// ---------------------------------------------------------------------------
// DualRealConvTasNet — round 3: round 2 + dec3 out-of-range tap guard.
//
// Layouts:
//  bf16 activations (conv chain): [batch][row 2064][512 c], data at row RHALO+t,
//    c contiguous. Pad rows zeroed each call.
//  fp32 activations (TCN chain):  [batch][chan][row ST], data at col HALO+t.
//    fp32 pads hold harness poison (-3e-13) — numerically benign.
//  d2 overlays memory written earlier in the launch -> its pad COLUMNS are
//  stale O(1) garbage; dec3 now guards its taps to [0, Tin) instead.
// ---------------------------------------------------------------------------

typedef unsigned short u16;
typedef __attribute__((ext_vector_type(8))) short bf16x8_t;
typedef __attribute__((ext_vector_type(4))) float f32x4_t;

#define ST    2064
#define HALO  8
#define TR    2064   // bf16 tensor rows
#define RHALO 8

// ---- workspace layout ----
#define U_F0H   0ULL          //  8,454,144 u16  [8][2064][512]
#define U_F1H   8454144ULL    //  8,454,144 u16
#define F_F2    8454144ULL    //  8,454,144 f32  [8][512][2064]
#define F_D2    0ULL          // 16,908,288 f32  [16][512][2064] (overlay)
#define U_YH    33816576ULL   // 16,908,288 u16  [16][2064][512]
#define U_D1H   50724864ULL   // 16,908,288 u16
#define F_O     33816576ULL   //  2,113,536 f32  [8][128][2064]
#define F_GA    35930112ULL   //    528,384 f32
#define F_GB    36458496ULL   //    528,384 f32
#define F_W     36986880ULL   // fp32 weight region
#define W_MGIN  0ULL          // [512][128]
#define W_MGOUT 65536ULL      // [128][1024]
#define W_W1T   196608ULL     // [24][128][32]
#define W_WSUMT 294912ULL     // [24][32][128]
#define W_BSUM  393216ULL     // [24][128]
#define U_WB    74766336ULL   // bf16 conv weights: 4 x [3][512][512]
// total ~156 MB

__device__ __forceinline__ float prelu_f(float x, float a) { return x >= 0.f ? x : a * x; }
__device__ __forceinline__ u16 f2b(float f) {
    unsigned u = __float_as_uint(f);
    return (u16)((u + 0x7FFF + ((u >> 16) & 1)) >> 16);
}

// ---------------------------------------------------------------------------
// Weight prep. task = blockIdx.y (0..8).
// ---------------------------------------------------------------------------
__global__ __launch_bounds__(256) void prep_weights(
    const float* __restrict__ ew1, const float* __restrict__ ew2,
    const float* __restrict__ dw1, const float* __restrict__ dw2,
    const float* __restrict__ mgin_w, const float* __restrict__ mgout_w,
    const float* __restrict__ bw1, const float* __restrict__ brw,
    const float* __restrict__ brb, const float* __restrict__ bsw,
    const float* __restrict__ bsb, float* __restrict__ wsf, u16* __restrict__ wsb)
{
    const int task = blockIdx.y;
    const int idx  = blockIdx.x * 256 + threadIdx.x;
    const int stride = gridDim.x * 256;
    if (task < 4) {
        // conv weights -> bf16 [j][o][c]; dec: flip tap + swap in/out
        const float* src = (task == 0) ? ew1 : (task == 1) ? ew2 : (task == 2) ? dw1 : dw2;
        u16* dst = wsb + U_WB + (size_t)task * 786432ULL;
        const bool dec = (task >= 2);
        for (int n = idx; n < 786432; n += stride) {
            int j = n >> 18, o = (n >> 9) & 511, c = n & 511;
            float v = dec ? src[(size_t)c * 1536 + o * 3 + (2 - j)]
                          : src[(size_t)o * 1536 + c * 3 + j];
            dst[n] = f2b(v);
        }
    } else if (task == 4) {          // mg_in_w [128][512] -> [512][128]
        float* dst = wsf + F_W + W_MGIN;
        for (int n = idx; n < 65536; n += stride) {
            int o = n & 127, c = n >> 7;
            dst[n] = mgin_w[(size_t)o * 512 + c];
        }
    } else if (task == 5) {          // mg_out_w [1024][128] -> [128][1024]
        float* dst = wsf + F_W + W_MGOUT;
        for (int n = idx; n < 131072; n += stride) {
            int m = n & 1023, c = n >> 10;
            dst[n] = mgout_w[(size_t)m * 128 + c];
        }
    } else if (task == 6) {          // blk_w1 [24][32][128] -> [24][128][32]
        float* dst = wsf + F_W + W_W1T;
        for (int n = idx; n < 98304; n += stride) {
            int cc = n & 31, C = (n >> 5) & 127, i = n >> 12;
            dst[n] = bw1[(size_t)i * 4096 + cc * 128 + C];
        }
    } else if (task == 7) {          // wsumT[i][cc][C] = sw (+ rw if i<23)
        float* dst = wsf + F_W + W_WSUMT;
        for (int n = idx; n < 98304; n += stride) {
            int C = n & 127, cc = (n >> 7) & 31, i = n >> 12;
            float v = bsw[(size_t)i * 4096 + C * 32 + cc];
            if (i < 23) v += brw[(size_t)i * 4096 + C * 32 + cc];
            dst[n] = v;
        }
    } else {                         // bsum[i][C]
        float* dst = wsf + F_W + W_BSUM;
        for (int n = idx; n < 3072; n += stride) {
            int i = n >> 7;
            float v = bsb[n];
            if (i < 23) v += brb[n];
            dst[n] = v;
        }
    }
}

// ---------------------------------------------------------------------------
// Zero the pad rows of a bf16 [batch][2064][512] tensor.
// ---------------------------------------------------------------------------
__global__ __launch_bounds__(256) void zero_pads(u16* __restrict__ base, int Treal)
{
    const int pr = blockIdx.y;
    const int row = (pr < RHALO) ? pr : (Treal + pr);
    ((unsigned*)(base + ((size_t)blockIdx.x * TR + row) * 512))[threadIdx.x] = 0u;
}

// ---------------------------------------------------------------------------
// Encoder conv0: 1->512, k16 s8 -> bf16 [t][c]. grid (8, 64, 8)
// ---------------------------------------------------------------------------
__global__ __launch_bounds__(256) void enc0_kernel(
    const float* __restrict__ xr, const float* __restrict__ xi,
    const float* __restrict__ w0, u16* __restrict__ f0h)
{
    const int t  = blockIdx.x * 256 + threadIdx.x;
    const int c0 = blockIdx.y * 8;
    const int b  = blockIdx.z;
    if (t >= 1999) return;
    const float* x = (b < 4) ? (xr + (size_t)b * 16000) : (xi + (size_t)(b - 4) * 16000);
    float xv[16];
    const int base = t * 8;
#pragma unroll
    for (int k = 0; k < 16; k++) xv[k] = x[base + k];
    union { u16 u[8]; uint4 v; } p;
#pragma unroll
    for (int cq = 0; cq < 8; cq++) {
        const float* w = w0 + (size_t)(c0 + cq) * 16;
        float acc = 0.f;
#pragma unroll
        for (int k = 0; k < 16; k++) acc = fmaf(xv[k], w[k], acc);
        p.u[cq] = f2b(acc);
    }
    *(uint4*)&f0h[((size_t)b * TR + RHALO + t) * 512 + c0] = p.v;
}

// ---------------------------------------------------------------------------
// bf16 MFMA conv3 (+PReLU). Tile 128o x 128t, BK=32, j inner.
// JOFF: input row offset (0 = valid conv, -2 = tconv-as-conv form).
// OUTF32=0: bf16 [t][c] out. OUTF32=1: fp32 [c][t] out (operand-swap).
// grid (16, 4, batch)
// ---------------------------------------------------------------------------
template <int JOFF, int OUTF32>
__global__ __launch_bounds__(256) void conv_mfma(
    const u16* __restrict__ in, u16* __restrict__ out16, float* __restrict__ out32,
    const u16* __restrict__ wM, const float* __restrict__ alpha_p, int Tout)
{
    __shared__ __align__(16) u16 As[15360];   // [j][128 o][40]
    __shared__ __align__(16) u16 Bs[5200];    // [130 t][40]
    const int tid  = threadIdx.x;
    const int t0   = blockIdx.x * 128;
    const int ob   = blockIdx.y * 128;
    const int b    = blockIdx.z;
    const int l15  = tid & 15;
    const int quad = (tid >> 4) & 3;
    const int wave = tid >> 6;
    const int wm   = (wave & 1) * 64;
    const int wn   = (wave >> 1) * 64;
    const u16* inb = in + (size_t)b * TR * 512;

    f32x4_t acc[4][4];
#pragma unroll
    for (int i = 0; i < 4; i++)
#pragma unroll
        for (int k = 0; k < 4; k++) acc[i][k] = (f32x4_t){0.f, 0.f, 0.f, 0.f};

    for (int c0 = 0; c0 < 512; c0 += 32) {
        for (int v = tid; v < 1536; v += 256) {
            int j = v >> 9, r = (v >> 2) & 127, seg = v & 3;
            *(uint4*)&As[j * 5120 + r * 40 + seg * 8] =
                *(const uint4*)&wM[((size_t)(j * 512 + ob + r)) * 512 + c0 + seg * 8];
        }
        for (int v = tid; v < 520; v += 256) {
            int r = v >> 2, seg = v & 3;
            int row = RHALO + t0 + JOFF + r;
            *(uint4*)&Bs[r * 40 + seg * 8] =
                *(const uint4*)&inb[(size_t)row * 512 + c0 + seg * 8];
        }
        __syncthreads();
#pragma unroll
        for (int j = 0; j < 3; j++) {
            bf16x8_t aw[4], bi[4];
#pragma unroll
            for (int mf = 0; mf < 4; mf++)
                aw[mf] = *(const bf16x8_t*)&As[j * 5120 + (wm + mf * 16 + l15) * 40 + quad * 8];
#pragma unroll
            for (int nf = 0; nf < 4; nf++)
                bi[nf] = *(const bf16x8_t*)&Bs[(wn + nf * 16 + l15 + j) * 40 + quad * 8];
#pragma unroll
            for (int mf = 0; mf < 4; mf++)
#pragma unroll
                for (int nf = 0; nf < 4; nf++) {
                    if (OUTF32)
                        acc[mf][nf] = __builtin_amdgcn_mfma_f32_16x16x32_bf16(
                            bi[nf], aw[mf], acc[mf][nf], 0, 0, 0);
                    else
                        acc[mf][nf] = __builtin_amdgcn_mfma_f32_16x16x32_bf16(
                            aw[mf], bi[nf], acc[mf][nf], 0, 0, 0);
                }
        }
        __syncthreads();
    }

    const float alpha = *alpha_p;
    if (!OUTF32) {
        // D[m=o][n=t]: col(lane&15)=t, row(quad*4+reg)=o
#pragma unroll
        for (int mf = 0; mf < 4; mf++)
#pragma unroll
            for (int nf = 0; nf < 4; nf++) {
                const int t = t0 + wn + nf * 16 + l15;
                if (t < Tout) {
                    const int c = ob + wm + mf * 16 + quad * 4;
                    f32x4_t a = acc[mf][nf];
                    ushort4 s;
                    s.x = f2b(prelu_f(a.x, alpha));
                    s.y = f2b(prelu_f(a.y, alpha));
                    s.z = f2b(prelu_f(a.z, alpha));
                    s.w = f2b(prelu_f(a.w, alpha));
                    *(ushort4*)&out16[((size_t)b * TR + RHALO + t) * 512 + c] = s;
                }
            }
    } else {
        // D[m=t][n=o]: col(lane&15)=o, row(quad*4+reg)=t
#pragma unroll
        for (int mf = 0; mf < 4; mf++)
#pragma unroll
            for (int nf = 0; nf < 4; nf++) {
                const int o  = ob + wm + mf * 16 + l15;
                const int tb = t0 + wn + nf * 16 + quad * 4;
                f32x4_t a = acc[mf][nf];
                float v0 = prelu_f(a.x, alpha), v1 = prelu_f(a.y, alpha);
                float v2 = prelu_f(a.z, alpha), v3 = prelu_f(a.w, alpha);
                float* p = out32 + ((size_t)(b * 512 + o)) * ST + HALO + tb;
                if (tb + 3 < Tout) {
                    *(float4*)p = make_float4(v0, v1, v2, v3);
                } else {
                    if (tb + 0 < Tout) p[0] = v0;
                    if (tb + 1 < Tout) p[1] = v1;
                    if (tb + 2 < Tout) p[2] = v2;
                    if (tb + 3 < Tout) p[3] = v3;
                }
            }
    }
}

// ---------------------------------------------------------------------------
// mg_in: o = mg_in_w @ f2 + b (512->128), fused g0 = prelu(pw1_0(o)).
// grid (32, 8)
// ---------------------------------------------------------------------------
__global__ __launch_bounds__(256) void mgin_kernel(
    const float* __restrict__ f2, float* __restrict__ o_buf, float* __restrict__ g_out,
    const float* __restrict__ wT, const float* __restrict__ bias,
    const float* __restrict__ w1T0, const float* __restrict__ b1_0,
    const float* __restrict__ a1_0)
{
    __shared__ float Bs[16][64];
    __shared__ float As[16][128];
    __shared__ float o_lds[128][64];
    const int tid = threadIdx.x;
    const int t0  = blockIdx.x * 64;
    const int b   = blockIdx.y;
    const float* f2b_ = f2 + (size_t)b * 512 * ST + HALO + t0;

    float acc[8][4];
#pragma unroll
    for (int i = 0; i < 8; i++)
#pragma unroll
        for (int k = 0; k < 4; k++) acc[i][k] = 0.f;
    const int tx = tid & 15, ty = tid >> 4;

    for (int c0 = 0; c0 < 512; c0 += 16) {
        {
            int c = tid >> 4, p = tid & 15;
            *(float4*)(&Bs[c][p * 4]) = *(const float4*)(f2b_ + (size_t)(c0 + c) * ST + p * 4);
        }
#pragma unroll
        for (int r = 0; r < 2; r++) {
            int n4 = tid + r * 256;
            int c = n4 >> 5, m4 = n4 & 31;
            *(float4*)(&As[c][m4 * 4]) = *(const float4*)(wT + (size_t)(c0 + c) * 128 + m4 * 4);
        }
        __syncthreads();
#pragma unroll 2
        for (int c = 0; c < 16; c++) {
            float4 bv = *(const float4*)(&Bs[c][tx * 4]);
            float a[8];
            *(float4*)(&a[0]) = *(const float4*)(&As[c][ty * 8]);
            *(float4*)(&a[4]) = *(const float4*)(&As[c][ty * 8 + 4]);
#pragma unroll
            for (int oi = 0; oi < 8; oi++) {
                acc[oi][0] = fmaf(a[oi], bv.x, acc[oi][0]);
                acc[oi][1] = fmaf(a[oi], bv.y, acc[oi][1]);
                acc[oi][2] = fmaf(a[oi], bv.z, acc[oi][2]);
                acc[oi][3] = fmaf(a[oi], bv.w, acc[oi][3]);
            }
        }
        __syncthreads();
    }

    const int tb = t0 + tx * 4;
#pragma unroll
    for (int oi = 0; oi < 8; oi++) {
        const int o = ty * 8 + oi;
        const float bo = bias[o];
        float vv[4];
#pragma unroll
        for (int kk = 0; kk < 4; kk++) vv[kk] = acc[oi][kk] + bo;
        *(float4*)(&o_lds[o][tx * 4]) = make_float4(vv[0], vv[1], vv[2], vv[3]);
        float* orow = o_buf + (size_t)(b * 128 + o) * ST + HALO + tb;
        if (tb + 3 < 1995) {
            *(float4*)orow = make_float4(vv[0], vv[1], vv[2], vv[3]);
        } else {
#pragma unroll
            for (int kk = 0; kk < 4; kk++)
                if (tb + kk < 1995) orow[kk] = vv[kk];
        }
    }
    __syncthreads();

    const int t = tid & 63, cg = tid >> 6;
    const float a1 = *a1_0;
    float acc2[8];
#pragma unroll
    for (int q = 0; q < 8; q++) acc2[q] = b1_0[cg * 8 + q];
    for (int C = 0; C < 128; C++) {
        const float ov = o_lds[C][t];
        const float4* wr = (const float4*)(w1T0 + (size_t)C * 32 + cg * 8);
        float4 w0 = wr[0], w1 = wr[1];
        acc2[0] = fmaf(w0.x, ov, acc2[0]); acc2[1] = fmaf(w0.y, ov, acc2[1]);
        acc2[2] = fmaf(w0.z, ov, acc2[2]); acc2[3] = fmaf(w0.w, ov, acc2[3]);
        acc2[4] = fmaf(w1.x, ov, acc2[4]); acc2[5] = fmaf(w1.y, ov, acc2[5]);
        acc2[6] = fmaf(w1.z, ov, acc2[6]); acc2[7] = fmaf(w1.w, ov, acc2[7]);
    }
    const int tt = t0 + t;
    if (tt < 1995) {
#pragma unroll
        for (int q = 0; q < 8; q++)
            g_out[(size_t)(b * 32 + cg * 8 + q) * ST + HALO + tt] = prelu_f(acc2[q], a1);
    }
}

// ---------------------------------------------------------------------------
// One TCN block. grid (32, 8)
// ---------------------------------------------------------------------------
__global__ __launch_bounds__(256) void tcn_kernel(
    const float* __restrict__ g_in, float* __restrict__ g_out, float* __restrict__ o_buf,
    const float* __restrict__ dw, const float* __restrict__ db, const float* __restrict__ a2p,
    const float* __restrict__ wsumT, const float* __restrict__ bsum,
    const float* __restrict__ w1T, const float* __restrict__ b1,
    const float* __restrict__ a1p, int dil, int has_next)
{
    __shared__ float h_lds[32][64];
    __shared__ float o_lds[128][64];
    __shared__ float wsum_lds[4096];
    __shared__ float w1_lds[4096];
    const int tid = threadIdx.x;
    const int t0  = blockIdx.x * 64;
    const int b   = blockIdx.y;

    for (int i = tid; i < 4096; i += 256) wsum_lds[i] = wsumT[i];
    if (has_next)
        for (int i = tid; i < 4096; i += 256) w1_lds[i] = w1T[i];

    const int t = tid & 63, grp = tid >> 6;
    const int tt = t0 + t;

    {
        const float a2 = *a2p;
#pragma unroll
        for (int q = 0; q < 8; q++) {
            const int cc = grp * 8 + q;
            const float* grow = g_in + (size_t)(b * 32 + cc) * ST + HALO;
            const float w0 = dw[cc * 3 + 0], w1v = dw[cc * 3 + 1], w2 = dw[cc * 3 + 2];
            float s = db[cc] + w1v * grow[tt];
            const int tm = tt - dil;
            if (tm >= 0) s = fmaf(w0, grow[tm], s);
            const int tp = tt + dil;
            if (tp < 1995) s = fmaf(w2, grow[tp], s);
            h_lds[cc][t] = prelu_f(s, a2);
        }
    }
    __syncthreads();

    {
        float hv[32];
#pragma unroll
        for (int cc = 0; cc < 32; cc++) hv[cc] = h_lds[cc][t];
        float s[32];
        const float* orow = o_buf + (size_t)(b * 128 + grp * 32) * ST + HALO + tt;
#pragma unroll
        for (int q = 0; q < 32; q++) s[q] = bsum[grp * 32 + q] + orow[(size_t)q * ST];
        for (int cc = 0; cc < 32; cc++) {
            const float h = hv[cc];
            const float4* wrow = (const float4*)&wsum_lds[cc * 128 + grp * 32];
#pragma unroll
            for (int q4 = 0; q4 < 8; q4++) {
                float4 w = wrow[q4];
                s[q4 * 4 + 0] = fmaf(w.x, h, s[q4 * 4 + 0]);
                s[q4 * 4 + 1] = fmaf(w.y, h, s[q4 * 4 + 1]);
                s[q4 * 4 + 2] = fmaf(w.z, h, s[q4 * 4 + 2]);
                s[q4 * 4 + 3] = fmaf(w.w, h, s[q4 * 4 + 3]);
            }
        }
#pragma unroll
        for (int q = 0; q < 32; q++) {
            const int C = grp * 32 + q;
            o_lds[C][t] = s[q];
            if (tt < 1995) o_buf[(size_t)(b * 128 + C) * ST + HALO + tt] = s[q];
        }
    }
    if (!has_next) return;
    __syncthreads();

    {
        const int ccb = grp * 8;
        const float a1 = *a1p;
        float acc2[8];
#pragma unroll
        for (int q = 0; q < 8; q++) acc2[q] = b1[ccb + q];
        for (int C = 0; C < 128; C++) {
            const float ov = o_lds[C][t];
            const float4* wr = (const float4*)&w1_lds[C * 32 + ccb];
            float4 w0 = wr[0], w1v = wr[1];
            acc2[0] = fmaf(w0.x, ov, acc2[0]);  acc2[1] = fmaf(w0.y, ov, acc2[1]);
            acc2[2] = fmaf(w0.z, ov, acc2[2]);  acc2[3] = fmaf(w0.w, ov, acc2[3]);
            acc2[4] = fmaf(w1v.x, ov, acc2[4]); acc2[5] = fmaf(w1v.y, ov, acc2[5]);
            acc2[6] = fmaf(w1v.z, ov, acc2[6]); acc2[7] = fmaf(w1v.w, ov, acc2[7]);
        }
        const int tt2 = t0 + t;
        if (tt2 < 1995) {
#pragma unroll
            for (int q = 0; q < 8; q++)
                g_out[(size_t)(b * 32 + ccb + q) * ST + HALO + tt2] = prelu_f(acc2[q], a1);
        }
    }
}

// ---------------------------------------------------------------------------
// mask + multiply -> y bf16 [t][c] via LDS transpose. grid (32, 4, 8)
// ---------------------------------------------------------------------------
__global__ __launch_bounds__(256) void mask_kernel(
    const float* __restrict__ o_buf, const float* __restrict__ f2, u16* __restrict__ yh,
    const float* __restrict__ wT, const float* __restrict__ mb,
    const float* __restrict__ a_out_p)
{
    __shared__ __align__(16) char smem[65536];
    float (*o_lds)[64]  = (float (*)[64])smem;
    float (*w_lds)[256] = (float (*)[256])(smem + 32768);
    u16* tile = (u16*)smem;             // [64 t][280] (overlay, used after final sync)

    const int tid = threadIdx.x;
    const int t0  = blockIdx.x * 64;
    const int m0  = blockIdx.y * 256;
    const int b   = blockIdx.z;
    const float ao = *a_out_p;

#pragma unroll
    for (int r = 0; r < 8; r++) {
        int n4 = tid + r * 256;
        int C = n4 >> 4, p = n4 & 15;
        float4 v = *(const float4*)(o_buf + (size_t)(b * 128 + C) * ST + HALO + t0 + p * 4);
        v.x = prelu_f(v.x, ao); v.y = prelu_f(v.y, ao);
        v.z = prelu_f(v.z, ao); v.w = prelu_f(v.w, ao);
        *(float4*)(&o_lds[C][p * 4]) = v;
    }

    float acc[16][4];
#pragma unroll
    for (int i = 0; i < 16; i++)
#pragma unroll
        for (int k = 0; k < 4; k++) acc[i][k] = 0.f;
    const int tx = tid & 15, my = tid >> 4;

    for (int C0 = 0; C0 < 128; C0 += 32) {
#pragma unroll
        for (int r = 0; r < 8; r++) {
            int n4 = tid + r * 256;
            int c = n4 >> 6, m4 = n4 & 63;
            *(float4*)(&w_lds[c][m4 * 4]) =
                *(const float4*)(wT + (size_t)(C0 + c) * 1024 + m0 + m4 * 4);
        }
        __syncthreads();
#pragma unroll 2
        for (int c = 0; c < 32; c++) {
            float4 bv = *(const float4*)(&o_lds[C0 + c][tx * 4]);
            float a[16];
            *(float4*)(&a[0])  = *(const float4*)(&w_lds[c][my * 16 + 0]);
            *(float4*)(&a[4])  = *(const float4*)(&w_lds[c][my * 16 + 4]);
            *(float4*)(&a[8])  = *(const float4*)(&w_lds[c][my * 16 + 8]);
            *(float4*)(&a[12]) = *(const float4*)(&w_lds[c][my * 16 + 12]);
#pragma unroll
            for (int mm = 0; mm < 16; mm++) {
                acc[mm][0] = fmaf(a[mm], bv.x, acc[mm][0]);
                acc[mm][1] = fmaf(a[mm], bv.y, acc[mm][1]);
                acc[mm][2] = fmaf(a[mm], bv.z, acc[mm][2]);
                acc[mm][3] = fmaf(a[mm], bv.w, acc[mm][3]);
            }
        }
        __syncthreads();
    }

    const int tb = t0 + tx * 4;
#pragma unroll
    for (int mm = 0; mm < 16; mm++) {
        const int mi = m0 + my * 16 + mm;
        const float bb = mb[mi];
        const int F = mi & 511;
        const float* f2row = f2 + (size_t)(b * 512 + F) * ST + HALO + tb;
#pragma unroll
        for (int kk = 0; kk < 4; kk++) {
            const float mval = 1.f / (1.f + __expf(-(acc[mm][kk] + bb)));
            acc[mm][kk] = mval * f2row[kk];
        }
    }
#pragma unroll
    for (int kk = 0; kk < 4; kk++) {
        const int row = tx * 4 + kk;
#pragma unroll
        for (int half = 0; half < 2; half++) {
            union { u16 u[8]; uint4 v; } p;
#pragma unroll
            for (int q = 0; q < 8; q++) p.u[q] = f2b(acc[half * 8 + q][kk]);
            *(uint4*)&tile[row * 280 + my * 16 + half * 8] = p.v;
        }
    }
    __syncthreads();
    const int F0 = m0 & 511, sIdx = m0 >> 9;
    u16* ybase = yh + ((size_t)(b * 2 + sIdx) * TR) * 512;
    for (int i = tid; i < 2048; i += 256) {
        const int row = i >> 5, seg = i & 31;
        const int t = t0 + row;
        if (t < 1995)
            *(uint4*)&ybase[(size_t)(RHALO + t) * 512 + F0 + seg * 8] =
                *(const uint4*)&tile[row * 280 + seg * 8];
    }
}

// ---------------------------------------------------------------------------
// Decoder tconv3: 512->1, k16 s8. Out-of-range taps read as 0 (d2 pads are
// stale memory, NOT zero — this guard restores tconv zero-pad semantics).
// grid (63, 16)
// ---------------------------------------------------------------------------
__global__ __launch_bounds__(256) void dec3_kernel(
    const float* __restrict__ d2, const float* __restrict__ w3, float* __restrict__ out)
{
    __shared__ float tile[512][34];
    const int tid = threadIdx.x;
    const int bb  = blockIdx.y;
    const int tau0 = blockIdx.x * 256;
    const int tbase = (tau0 >> 3) - 1;
    const float* src = d2 + (size_t)bb * 512 * ST + HALO + tbase;
    for (int n = tid; n < 512 * 34; n += 256) {
        int o = n / 34, i = n % 34;
        const int tg = tbase + i;
        tile[o][i] = (tg >= 0 && tg < 1999) ? src[(size_t)o * ST + i] : 0.f;
    }
    __syncthreads();

    const int tau = tau0 + tid;
    if (tau >= 16000) return;
    const int k1 = tau & 7;
    const int t1l = (tid >> 3) + 1;
    float acc = 0.f;
#pragma unroll 8
    for (int o = 0; o < 512; o++) {
        acc = fmaf(tile[o][t1l],     w3[o * 16 + k1],     acc);
        acc = fmaf(tile[o][t1l - 1], w3[o * 16 + 8 + k1], acc);
    }
    const int p = bb >> 1, s = bb & 1;
    out[(size_t)(p * 2 + s) * 16000 + tau] = acc;
}

// ---------------------------------------------------------------------------
extern "C" void kernel_launch(void* const* d_in, const int* in_sizes, int n_in,
                              void* d_out, int out_size, void* d_ws, size_t ws_size,
                              hipStream_t stream)
{
    (void)in_sizes; (void)n_in; (void)out_size; (void)ws_size;
    float* ws  = (float*)d_ws;
    u16*   wsu = (u16*)d_ws;
    const float* x_real   = (const float*)d_in[0];
    const float* x_imag   = (const float*)d_in[1];
    const float* enc_w0   = (const float*)d_in[2];
    const float* enc_w1   = (const float*)d_in[3];
    const float* enc_w2   = (const float*)d_in[4];
    const float* enc_a    = (const float*)d_in[5];
    const float* mg_in_w  = (const float*)d_in[6];
    const float* mg_in_b  = (const float*)d_in[7];
    const float* blk_w1   = (const float*)d_in[8];
    const float* blk_b1   = (const float*)d_in[9];
    const float* blk_a1   = (const float*)d_in[10];
    const float* blk_dw   = (const float*)d_in[11];
    const float* blk_db   = (const float*)d_in[12];
    const float* blk_a2   = (const float*)d_in[13];
    const float* blk_rw   = (const float*)d_in[14];
    const float* blk_rb   = (const float*)d_in[15];
    const float* blk_sw   = (const float*)d_in[16];
    const float* blk_sb   = (const float*)d_in[17];
    const float* mg_out_a = (const float*)d_in[18];
    const float* mg_out_w = (const float*)d_in[19];
    const float* mg_out_b = (const float*)d_in[20];
    const float* dec_w1   = (const float*)d_in[21];
    const float* dec_w2   = (const float*)d_in[22];
    const float* dec_a    = (const float*)d_in[23];
    const float* dec_w3   = (const float*)d_in[24];
    float* out = (float*)d_out;

    u16*   f0h  = wsu + U_F0H;
    u16*   f1h  = wsu + U_F1H;
    float* f2   = ws  + F_F2;
    float* d2   = ws  + F_D2;
    u16*   yh   = wsu + U_YH;
    u16*   d1h  = wsu + U_D1H;
    float* obuf = ws  + F_O;
    float* gA   = ws  + F_GA;
    float* gB   = ws  + F_GB;
    float* WF   = ws  + F_W;
    u16*   WB   = wsu + U_WB;

    const dim3 blk(256);

    prep_weights<<<dim3(64, 9), blk, 0, stream>>>(enc_w1, enc_w2, dec_w1, dec_w2,
        mg_in_w, mg_out_w, blk_w1, blk_rw, blk_rb, blk_sw, blk_sb, ws, wsu);

    zero_pads<<<dim3(8, 65), blk, 0, stream>>>(f0h, 1999);
    zero_pads<<<dim3(8, 67), blk, 0, stream>>>(f1h, 1997);
    zero_pads<<<dim3(16, 69), blk, 0, stream>>>(yh, 1995);
    zero_pads<<<dim3(16, 67), blk, 0, stream>>>(d1h, 1997);

    enc0_kernel<<<dim3(8, 64, 8), blk, 0, stream>>>(x_real, x_imag, enc_w0, f0h);

    conv_mfma<0, 0><<<dim3(16, 4, 8), blk, 0, stream>>>(
        f0h, f1h, nullptr, WB + 0 * 786432, enc_a + 0, 1997);
    conv_mfma<0, 1><<<dim3(16, 4, 8), blk, 0, stream>>>(
        f1h, nullptr, f2, WB + 1 * 786432, enc_a + 1, 1995);

    mgin_kernel<<<dim3(32, 8), blk, 0, stream>>>(f2, obuf, gA, WF + W_MGIN, mg_in_b,
        WF + W_W1T, blk_b1, blk_a1);

    for (int i = 0; i < 24; i++) {
        const int dil = 1 << (i & 7);
        const int has_next = (i < 23) ? 1 : 0;
        const float* gi = (i & 1) ? gB : gA;
        float* go       = (i & 1) ? gA : gB;
        tcn_kernel<<<dim3(32, 8), blk, 0, stream>>>(gi, go, obuf,
            blk_dw + i * 96, blk_db + i * 32, blk_a2 + i,
            WF + W_WSUMT + (size_t)i * 4096, WF + W_BSUM + (size_t)i * 128,
            WF + W_W1T + (size_t)(has_next ? (i + 1) : 0) * 4096,
            blk_b1 + (has_next ? (i + 1) : 0) * 32,
            blk_a1 + (has_next ? (i + 1) : 0),
            dil, has_next);
    }

    mask_kernel<<<dim3(32, 4, 8), blk, 0, stream>>>(obuf, f2, yh,
        WF + W_MGOUT, mg_out_b, mg_out_a);

    conv_mfma<-2, 0><<<dim3(16, 4, 16), blk, 0, stream>>>(
        yh, d1h, nullptr, WB + 2 * 786432, dec_a + 0, 1997);
    conv_mfma<-2, 1><<<dim3(16, 4, 16), blk, 0, stream>>>(
        d1h, nullptr, d2, WB + 3 * 786432, dec_a + 1, 1999);

    dec3_kernel<<<dim3(63, 16), blk, 0, stream>>>(d2, dec_w3, out);
}